// Round 3
// baseline (493.491 us; speedup 1.0000x reference)
//
#include <hip/hip_runtime.h>

typedef short s16x8 __attribute__((ext_vector_type(8)));
typedef float f32x4 __attribute__((ext_vector_type(4)));

#define N_SAMPLES 65536
#define DIM 768
#define HID 384
#define NEXP 8
#define NCLS 8
#define JT 24   // HID/16
#define KT 24   // DIM/32
#define PHK 6   // k-steps per A-staging phase (4 phases x 6 = 24)
#define PHF 192 // floats per row per phase (PHK*32)

// workspace layout (bytes)
#define WS_CNT    0
#define WS_BUCKET 1024
#define WS_W1F    (WS_BUCKET + NEXP * N_SAMPLES * 4)   // 2,098,176

// RNE bf16 (prep only)
__device__ __forceinline__ unsigned short f2bf(float f) {
  union { float f; unsigned u; } v; v.f = f;
  unsigned r = v.u + 0x7fffu + ((v.u >> 16) & 1u);
  return (unsigned short)(r >> 16);
}

// fast half-up pair: 2x v_add + 1x v_perm = 1.5 VALU/element
// result: low16 = bf(a), high16 = bf(b)
__device__ __forceinline__ unsigned cvt2(float a, float b) {
  union { float f; unsigned u; } ua, ub;
  ua.f = a; ub.f = b;
  return __builtin_amdgcn_perm(ub.u + 0x8000u, ua.u + 0x8000u, 0x07060302u);
}

// lgkm-only barrier (CK block_sync_lds): does NOT drain vmcnt, so global
// register prefetches stay in flight across it.
#define LBAR asm volatile("s_waitcnt lgkmcnt(0)\n\ts_barrier" ::: "memory")

// W1[e][k=768][j=384] f32 -> W1F in MFMA A-fragment order:
// W1F[((e*JT+jt)*KT+kt)*64 + lane][i] = W1[e][kt*32+(lane>>4)*8+i][jt*16+(lane&15)]
__global__ void k_w1frag(const float* __restrict__ W1,
                         unsigned short* __restrict__ W1F,
                         int* __restrict__ cnt) {
  if (blockIdx.x == 0 && blockIdx.y == 0 && threadIdx.x < NEXP)
    cnt[threadIdx.x] = 0;
  const int e = blockIdx.x;
  const int unit = blockIdx.y * 4 + (threadIdx.x >> 6);   // (jt,kt) flat, 0..575
  const int lane = threadIdx.x & 63;
  const int jt = unit / KT, kt = unit % KT;
  const int j = jt * 16 + (lane & 15);
  const int k0 = kt * 32 + (lane >> 4) * 8;
  const float* src = W1 + ((size_t)e * DIM + k0) * HID + j;
  s16x8 v;
#pragma unroll
  for (int i = 0; i < 8; ++i) v[i] = (short)f2bf(src[(size_t)i * HID]);
  *(s16x8*)&W1F[(((size_t)e * JT * KT + unit) * 64 + lane) * 8] = v;
}

// bucket rows by expert
__global__ void k_scatter(const int* __restrict__ qt, int* __restrict__ cnt,
                          int* __restrict__ bucket) {
  __shared__ int lcnt[NEXP], lbase[NEXP];
  const int t = threadIdx.x;
  const int i = blockIdx.x * 256 + t;
  if (t < NEXP) lcnt[t] = 0;
  __syncthreads();
  const int e = qt[i];
  const int rank = atomicAdd(&lcnt[e], 1);
  __syncthreads();
  if (t < NEXP) lbase[t] = atomicAdd(&cnt[t], lcnt[t]);
  __syncthreads();
  bucket[(size_t)e * N_SAMPLES + lbase[e] + rank] = i;
}

// ---- A staging: per phase each thread loads 48 CONTIGUOUS floats (192B)
// of its row; 4 threads/row = 768B contiguous burst per row per phase.
// This is the DRAM-page-locality fix: rounds 0-2 read rows in 128B pieces
// separated by ~2.8us -> every touch was a fresh page activation, capping
// HBM at ~1.3-1.5 TB/s across three different wait schedules. ----

// A tile buffer: [64 rows][24 slots of 16B], slot' = slot ^ (row&7).
// Row stride 384B (bank-aligned); the XOR spreads both ds_write_b128 and
// ds_read_b128 evenly over all 32 banks (8 lanes/4-bank group = minimum).

#define ALD(S, I) av##S = app[I];
#define ALOAD12(APTR, PH)                                                   \
  { const float4* app = (const float4*)((APTR) + (PH) * PHF + aq * 48);     \
    ALD(0,0) ALD(1,1) ALD(2,2) ALD(3,3) ALD(4,4) ALD(5,5)                   \
    ALD(6,6) ALD(7,7) ALD(8,8) ALD(9,9) ALD(10,10) ALD(11,11) }

// pair (av2m, av2m+1) = floats [48*aq+8m, +8) -> slot 6*aq+m, swizzled
#define CST(BUF, M, E, O)                                                   \
  { uint4 pk_ = {cvt2(av##E.x, av##E.y), cvt2(av##E.z, av##E.w),            \
                 cvt2(av##O.x, av##O.y), cvt2(av##O.z, av##O.w)};           \
    *(uint4*)&(BUF)[aw_base + (((6 * aq + (M)) ^ arsw) << 3)] = pk_; }
#define CVTSTORE(BUF) \
  CST(BUF,0,0,1) CST(BUF,1,2,3) CST(BUF,2,4,5) \
  CST(BUF,3,6,7) CST(BUF,4,8,9) CST(BUF,5,10,11)

// 6 coalesced b128 fragment loads of W1F for k-step KS (from e-pinned L2)
#define WLOADN(WF, KS)                                                      \
  _Pragma("unroll") for (int ni = 0; ni < 6; ++ni)                          \
      WF[ni] = *(const s16x8*)(wfbase + ((size_t)ni * KT + (KS)) * 512);

// 4 swizzled ds_read_b128 (x frags) + 24 MFMA; WF = A-operand (j), x = B (m)
#define COMPUTE(AS, WF, KSL)                                                \
  { _Pragma("unroll") for (int mi = 0; mi < 4; ++mi) {                      \
      s16x8 xfr = *(const s16x8*)&(AS)[(mi * 16 + lrow) * 192 +             \
                                       (((((KSL) * 4) + quad) ^ lsw) << 3)];\
      _Pragma("unroll") for (int ni = 0; ni < 6; ++ni)                      \
          acc[mi][ni] = __builtin_amdgcn_mfma_f32_16x16x32_bf16(            \
              WF[ni], xfr, acc[mi][ni], 0, 0, 0); } }

// one k-step: consume W slot (loaded 2 steps ago, covers L2 latency),
// then refill it for KSG+2. All indices are literals after expansion.
#define KS(AS, KSG, WF)                                                     \
  COMPUTE(AS, WF, (KSG) % PHK)                                              \
  if ((KSG) + 2 < 24) { WLOADN(WF, (KSG) + 2) }

#define PHASE(AS, K0)                                                       \
  KS(AS, (K0)+0, wfA) KS(AS, (K0)+1, wfB) KS(AS, (K0)+2, wfA)               \
  KS(AS, (K0)+3, wfB) KS(AS, (K0)+4, wfA) KS(AS, (K0)+5, wfB)

// block = (expert e -> pinned XCD, 64 gathered rows, all 384 H)
__global__ __launch_bounds__(256, 2) void k_moe_gemm(
    const float* __restrict__ x, const unsigned short* __restrict__ W1F,
    const float* __restrict__ b1, const float* __restrict__ W2,
    const float* __restrict__ b2, const int* __restrict__ cnt,
    const int* __restrict__ bucket, float* __restrict__ out) {
  // As0/As1 = [64][192] bf16 phase buffers (24KB each); Hs overlays both.
  __shared__ __align__(16) short smem[25088];
  __shared__ __align__(16) short W2s[16 * 392];
  __shared__ float b1s[HID];
  __shared__ float b2s[NCLS];
  short* As0 = smem;
  short* As1 = smem + 12288;
  short* Hs  = smem;            // [64 m][392 j] bf16

  const int e = blockIdx.x;
  const int n_e = cnt[e];
  if (n_e <= 0) return;         // uniform exit, no barrier crossed yet
  const int t = threadIdx.x;
  const int lane = t & 63;
  const int wave = t >> 6;
  const int lrow = lane & 15;
  const int quad = lane >> 4;
  const int ar = t >> 2;        // A staging row (0..63)
  const int aq = t & 3;         // A staging chunk (48 floats)
  const int arsw = ar & 7;      // write-side swizzle key
  const int lsw = lrow & 7;     // read-side swizzle key
  const int aw_base = ar * 192;

  for (int j = t; j < HID; j += 256) {
    b1s[j] = b1[e * HID + j];
    const float* wr = W2 + ((size_t)e * HID + j) * NCLS;
#pragma unroll
    for (int c = 0; c < NCLS; ++c) W2s[c * 392 + j] = (short)f2bf(wr[c]);
#pragma unroll
    for (int c = NCLS; c < 16; ++c) W2s[c * 392 + j] = 0;
  }
  if (t < NCLS) b2s[t] = b2[e * NCLS + t];

  // this wave's W1F base: jt = wave*6 + ni, per-kt stride 512 shorts
  const unsigned short* wfbase =
      W1F + ((size_t)(e * JT + wave * 6) * KT) * 512 + lane * 8;

  // first tile's gathered row index
  int aidx = 0;
  {
    const int rt0 = blockIdx.y;
    if (rt0 * 64 < n_e) {
      int slot = rt0 * 64 + ar;
      if (slot >= n_e) slot = n_e - 1;   // clamp: dup compute, masked store
      aidx = bucket[(size_t)e * N_SAMPLES + slot];
    }
  }

  float4 av0, av1, av2, av3, av4, av5, av6, av7, av8, av9, av10, av11;
  s16x8 wfA[6], wfB[6];

  // first tile phase-0 loads (subsequent tiles issue these during phase 3)
  ALOAD12(x + (size_t)aidx * DIM, 0)

  for (int rt = blockIdx.y; rt * 64 < n_e; rt += gridDim.y) {
    const int row0 = rt * 64;
    const float* ap = x + (size_t)aidx * DIM;

    // prologue: W prefetch first (so the CVTSTORE waits are counted),
    // then stage phase 0 from the already-in-flight av registers.
    WLOADN(wfA, 0) WLOADN(wfB, 1)
    CVTSTORE(As0)

    // prefetch next tile's bucket index; latency hides under the k-loop
    int aidx_n = aidx;
    {
      const int nrt = rt + gridDim.y;
      if (nrt * 64 < n_e) {
        int s = nrt * 64 + ar;
        if (s >= n_e) s = n_e - 1;
        aidx_n = bucket[(size_t)e * N_SAMPLES + s];
      }
    }

    f32x4 acc[4][6];
#pragma unroll
    for (int mi = 0; mi < 4; ++mi)
#pragma unroll
      for (int ni = 0; ni < 6; ++ni) acc[mi][ni] = (f32x4){0.f, 0.f, 0.f, 0.f};

    LBAR;   // As0 visible; av/W prefetches for later phases stay in flight

    // phase 0: compute ks 0..5 from As0; burst-load phase-1 A (768B/row)
    ALOAD12(ap, 1)
    PHASE(As0, 0)
    CVTSTORE(As1)
    LBAR;

    // phase 1: ks 6..11 from As1
    ALOAD12(ap, 2)
    PHASE(As1, 6)
    CVTSTORE(As0)
    LBAR;

    // phase 2: ks 12..17 from As0
    ALOAD12(ap, 3)
    PHASE(As0, 12)
    CVTSTORE(As1)
    LBAR;

    // phase 3: ks 18..23 from As1; issue NEXT tile's phase-0 loads so the
    // tile transition never stalls on HBM
    if ((rt + gridDim.y) * 64 < n_e) { ALOAD12(x + (size_t)aidx_n * DIM, 0) }
    PHASE(As1, 18)
    LBAR;   // As1 reads done; Hs (overlays As0+As1) safe to write

    // epilogue 1: bias+relu -> Hs[m][j]; acc: col(lane&15)=m, row(quad*4+r)=j
#pragma unroll
    for (int mi = 0; mi < 4; ++mi)
#pragma unroll
      for (int ni = 0; ni < 6; ++ni) {
        const int j = wave * 96 + ni * 16 + quad * 4;
        const float4 bb = *(const float4*)&b1s[j];
        float v0 = acc[mi][ni][0] + bb.x; v0 = v0 > 0.f ? v0 : 0.f;
        float v1 = acc[mi][ni][1] + bb.y; v1 = v1 > 0.f ? v1 : 0.f;
        float v2 = acc[mi][ni][2] + bb.z; v2 = v2 > 0.f ? v2 : 0.f;
        float v3 = acc[mi][ni][3] + bb.w; v3 = v3 > 0.f ? v3 : 0.f;
        uint2 pk = {cvt2(v0, v1), cvt2(v2, v3)};
        *(uint2*)&Hs[(mi * 16 + lrow) * 392 + j] = pk;
      }
    LBAR;

    // epilogue 2: layer-2 MFMA, M=64 (m-tile = wave), N=16 (8 valid), K=384
    {
      f32x4 acc2 = (f32x4){0.f, 0.f, 0.f, 0.f};
#pragma unroll
      for (int kk = 0; kk < 12; ++kk) {
        s16x8 af = *(const s16x8*)&Hs[(wave * 16 + lrow) * 392 + kk * 32 + quad * 8];
        s16x8 bf = *(const s16x8*)&W2s[lrow * 392 + kk * 32 + quad * 8];
        acc2 = __builtin_amdgcn_mfma_f32_16x16x32_bf16(af, bf, acc2, 0, 0, 0);
      }
      if (lrow < NCLS) {
        const float bb = b2s[lrow];
#pragma unroll
        for (int r = 0; r < 4; ++r) {
          const int m = wave * 16 + quad * 4 + r;
          if (row0 + m < n_e) {
            const int oi = bucket[(size_t)e * N_SAMPLES + row0 + m];
            out[(size_t)oi * NCLS + lrow] = acc2[r] + bb;
          }
        }
      }
    }
    LBAR;   // Hs reads done before next tile's staging overwrites it
    aidx = aidx_n;
  }
}

extern "C" void kernel_launch(void* const* d_in, const int* in_sizes, int n_in,
                              void* d_out, int out_size, void* d_ws, size_t ws_size,
                              hipStream_t stream) {
  const float* x  = (const float*)d_in[0];
  const float* W1 = (const float*)d_in[1];
  const float* b1 = (const float*)d_in[2];
  const float* W2 = (const float*)d_in[3];
  const float* b2 = (const float*)d_in[4];
  const int* qt   = (const int*)d_in[5];
  float* out = (float*)d_out;
  char* ws = (char*)d_ws;

  int* cnt = (int*)(ws + WS_CNT);
  int* bucket = (int*)(ws + WS_BUCKET);
  unsigned short* W1F = (unsigned short*)(ws + WS_W1F);

  k_w1frag<<<dim3(8, 144), dim3(256), 0, stream>>>(W1, W1F, cnt);
  k_scatter<<<dim3(256), dim3(256), 0, stream>>>(qt, cnt, bucket);
  k_moe_gemm<<<dim3(8, 64), dim3(256), 0, stream>>>(x, W1F, b1, W2, b2, cnt, bucket, out);
}

// Round 5
// 473.501 us; speedup vs baseline: 1.0422x; 1.0422x over previous
//
#include <hip/hip_runtime.h>

typedef short s16x8 __attribute__((ext_vector_type(8)));
typedef float f32x4 __attribute__((ext_vector_type(4)));

#define N_SAMPLES 65536
#define DIM 768
#define HID 384
#define NEXP 8
#define NCLS 8
#define JT 24   // HID/16
#define KT 24   // DIM/32

// workspace layout (bytes)
#define WS_CNT    0
#define WS_BUCKET 1024
#define WS_W1F    (WS_BUCKET + NEXP * N_SAMPLES * 4)   // 2,098,176

// RNE bf16 (prep only)
__device__ __forceinline__ unsigned short f2bf(float f) {
  union { float f; unsigned u; } v; v.f = f;
  unsigned r = v.u + 0x7fffu + ((v.u >> 16) & 1u);
  return (unsigned short)(r >> 16);
}

// fast half-up pair: 2x v_add + 1x v_perm; low16 = bf(a), high16 = bf(b)
__device__ __forceinline__ unsigned cvt2(float a, float b) {
  union { float f; unsigned u; } ua, ub;
  ua.f = a; ub.f = b;
  return __builtin_amdgcn_perm(ub.u + 0x8000u, ua.u + 0x8000u, 0x07060302u);
}

// raw barrier / counted waits / scheduler fences (all asm => loads and
// global_load_lds builtins cannot be reordered across them, so the static
// vmcnt counts below are exact)
#define SBAR  asm volatile("s_barrier" ::: "memory")
#define MFEN  asm volatile("" ::: "memory")
#define VMW(N) asm volatile("s_waitcnt vmcnt(" #N ")" ::: "memory")
#define LBAR asm volatile("s_waitcnt lgkmcnt(0)\n\ts_barrier" ::: "memory")

// HBM -> LDS direct DMA, 16B per lane, dest = uniform base + lane*16.
// Zero landing VGPRs: this is the fix for rounds 1-3's spill storms.
__device__ __forceinline__ void gload16(const void* g, void* l) {
  __builtin_amdgcn_global_load_lds(
      (const __attribute__((address_space(1))) void*)g,
      (__attribute__((address_space(3))) void*)l, 16, 0, 0);
}

// W1[e][k=768][j=384] f32 -> W1F in MFMA A-fragment order:
// W1F[((e*JT+jt)*KT+kt)*64 + lane][i] = W1[e][kt*32+(lane>>4)*8+i][jt*16+(lane&15)]
__global__ void k_w1frag(const float* __restrict__ W1,
                         unsigned short* __restrict__ W1F,
                         int* __restrict__ cnt) {
  if (blockIdx.x == 0 && blockIdx.y == 0 && threadIdx.x < NEXP)
    cnt[threadIdx.x] = 0;
  const int e = blockIdx.x;
  const int unit = blockIdx.y * 4 + (threadIdx.x >> 6);   // (jt,kt) flat, 0..575
  const int lane = threadIdx.x & 63;
  const int jt = unit / KT, kt = unit % KT;
  const int j = jt * 16 + (lane & 15);
  const int k0 = kt * 32 + (lane >> 4) * 8;
  const float* src = W1 + ((size_t)e * DIM + k0) * HID + j;
  s16x8 v;
#pragma unroll
  for (int i = 0; i < 8; ++i) v[i] = (short)f2bf(src[(size_t)i * HID]);
  *(s16x8*)&W1F[(((size_t)e * JT * KT + unit) * 64 + lane) * 8] = v;
}

// bucket rows by expert
__global__ void k_scatter(const int* __restrict__ qt, int* __restrict__ cnt,
                          int* __restrict__ bucket) {
  __shared__ int lcnt[NEXP], lbase[NEXP];
  const int t = threadIdx.x;
  const int i = blockIdx.x * 256 + t;
  if (t < NEXP) lcnt[t] = 0;
  __syncthreads();
  const int e = qt[i];
  const int rank = atomicAdd(&lcnt[e], 1);
  __syncthreads();
  if (t < NEXP) lbase[t] = atomicAdd(&cnt[t], lcnt[t]);
  __syncthreads();
  bucket[(size_t)e * N_SAMPLES + lbase[e] + rank] = i;
}

// ---- A staging via global_load_lds, phase = 4 k-steps = 128 f32 = 512B/row.
// Wave w instr i covers LDS bytes [i*4096 + w*1024, +1024) = rows
// {i*8+w*2, i*8+w*2+1} of the [64][128] f32 buffer (row stride 512B).
// Storage swizzle: LDS 16B-chunk c of row r holds global chunk c^(r&7)
// (applied by pre-swizzling the per-lane GLOBAL address; DMA dest linear).
// Each instr reads 2 full rows x 512B contiguous -> DRAM page efficiency.
#define GLOADPH(BUF, P)                                                     \
  _Pragma("unroll") for (int i = 0; i < 8; ++i)                             \
      gload16((const char*)x + off[i] + (P) * 512,                          \
              (char*)(BUF) + i * 4096 + wave * 1024);

// 6 coalesced b128 fragment loads of W1F for k-step KS (from e-pinned L2)
#define WLOADN(WF, KS)                                                      \
  _Pragma("unroll") for (int ni = 0; ni < 6; ++ni)                          \
      WF[ni] = *(const s16x8*)(wfbase + ((size_t)ni * KT + (KS)) * 512);

// per k-step: 8 swizzled f32 ds_read_b128 + cvt-on-read + 24 MFMA
#define COMPUTE4(BUF, WF, KL)                                               \
  { _Pragma("unroll") for (int mi = 0; mi < 4; ++mi) {                      \
      const char* rb_ = (const char*)(BUF) + (mi * 16 + lrow) * 512 + (KL) * 128; \
      float4 c0 = *(const float4*)(rb_ + o0);                               \
      float4 c1 = *(const float4*)(rb_ + o1);                               \
      union { uint4 u; s16x8 s; } xf;                                       \
      xf.u = (uint4){cvt2(c0.x, c0.y), cvt2(c0.z, c0.w),                    \
                     cvt2(c1.x, c1.y), cvt2(c1.z, c1.w)};                   \
      _Pragma("unroll") for (int ni = 0; ni < 6; ++ni)                      \
          acc[mi][ni] = __builtin_amdgcn_mfma_f32_16x16x32_bf16(            \
              WF[ni], xf.s, acc[mi][ni], 0, 0, 0); } }

#define KST(BUF, WF, KL, KSG)                                               \
  COMPUTE4(BUF, WF, KL)                                                     \
  if ((KSG) + 2 < 24) { WLOADN(WF, (KSG) + 2) }

#define PHASE4(BUF, P)                                                      \
  KST(BUF, wfA, 0, (P) * 4 + 0)                                             \
  KST(BUF, wfB, 1, (P) * 4 + 1)                                             \
  KST(BUF, wfA, 2, (P) * 4 + 2)                                             \
  KST(BUF, wfB, 3, (P) * 4 + 3)

// end of phase: all waves done reading BUFC -> DMA next+1 phase into it,
// counted-wait for next phase's DMA (never 0), barrier, fence.
#define PH_SYNC(BUFC, PN2, VN)                                              \
  SBAR;                                                                     \
  GLOADPH(BUFC, PN2)                                                        \
  VMW(VN); SBAR; MFEN;

// block = (expert e -> pinned XCD, 64 gathered rows, all 384 H)
__global__ __launch_bounds__(256, 2) void k_moe_gemm(
    const float* __restrict__ x, const unsigned short* __restrict__ W1F,
    const float* __restrict__ b1, const float* __restrict__ W2,
    const float* __restrict__ b2, const int* __restrict__ cnt,
    const int* __restrict__ bucket, float* __restrict__ out) {
  __shared__ __align__(16) short smem[32768];   // 64 KB: As0f|As1f, Hs overlay
  __shared__ __align__(16) short W2s[16 * 392];
  __shared__ float b1s[HID];
  __shared__ float b2s[NCLS];
  float* As0f = (float*)smem;                   // [64][128] f32, 32 KB
  float* As1f = (float*)(smem + 16384);
  short* Hs = smem;                             // [64 m][392 j] bf16

  const int e = blockIdx.x;
  const int n_e = cnt[e];
  if (n_e <= 0) return;         // uniform exit, no barrier crossed yet
  const int t = threadIdx.x;
  const int lane = t & 63;
  const int wave = t >> 6;
  const int lrow = lane & 15;
  const int quad = lane >> 4;
  const int lsw = lrow & 7;                     // read-side swizzle key
  const int o0 = ((quad * 2) ^ lsw) << 4;       // chunk offsets within k-step
  const int o1 = o0 ^ 16;
  const int rbase = wave * 2 + (lane >> 5);     // DMA row key (0..7)
  const int g16o = (((lane & 31) ^ rbase) << 4);// pre-swizzled col byte offset

  for (int j = t; j < HID; j += 256) {
    b1s[j] = b1[e * HID + j];
    const float* wr = W2 + ((size_t)e * HID + j) * NCLS;
#pragma unroll
    for (int c = 0; c < NCLS; ++c) W2s[c * 392 + j] = (short)f2bf(wr[c]);
#pragma unroll
    for (int c = NCLS; c < 16; ++c) W2s[c * 392 + j] = 0;
  }
  if (t < NCLS) b2s[t] = b2[e * NCLS + t];

  // this wave's W1F base: jt = wave*6 + ni, per-kt stride 512 shorts
  const unsigned short* wfbase =
      W1F + ((size_t)(e * JT + wave * 6) * KT) * 512 + lane * 8;

  // first tile's 8 per-lane DMA source offsets (rows rbase+8i, clamped)
  unsigned off[8];
#pragma unroll
  for (int i = 0; i < 8; ++i) {
    int s = blockIdx.y * 64 + rbase + 8 * i;
    if (s >= n_e) s = n_e - 1;
    off[i] = (unsigned)bucket[(size_t)e * N_SAMPLES + s] * 3072u + g16o;
  }

  for (int rt = blockIdx.y; rt * 64 < n_e; rt += 64) {
    const int row0 = rt * 64;

    // ---- prologue: ph0 DMA, ph1 DMA, W(0), W(1), next-tile bucket ----
    GLOADPH(As0f, 0)
    MFEN;
    GLOADPH(As1f, 1)
    MFEN;
    s16x8 wfA[6], wfB[6];
    WLOADN(wfA, 0)
    WLOADN(wfB, 1)
    int nraw[8];                 // next tile's row indices (always issued,
#pragma unroll                   // clamped, so vmcnt counts stay static)
    for (int i = 0; i < 8; ++i) {
      int s = row0 + 4096 + rbase + 8 * i;
      if (s >= n_e) s = n_e - 1;
      nraw[i] = bucket[(size_t)e * N_SAMPLES + s];
    }
    f32x4 acc[4][6];
#pragma unroll
    for (int mi = 0; mi < 4; ++mi)
#pragma unroll
      for (int ni = 0; ni < 6; ++ni) acc[mi][ni] = (f32x4){0.f, 0.f, 0.f, 0.f};
    // ph0 done; younger in flight: ph1(8) + wfA(6) + wfB(6) + bucket(8)
    VMW(28); SBAR; MFEN;

    PHASE4(As0f, 0) PH_SYNC(As0f, 2, 52)  // 52 = wf12+bkt8+W24+ph2's 8
    PHASE4(As1f, 1) PH_SYNC(As1f, 3, 32)  // 32 = W24 + next DMA 8
    PHASE4(As0f, 2) PH_SYNC(As0f, 4, 32)
    PHASE4(As1f, 3) PH_SYNC(As1f, 5, 32)
    PHASE4(As0f, 4)
    SBAR; VMW(24); SBAR; MFEN;            // ph5 resident (24 = W of phase 4)
    PHASE4(As1f, 5)
    SBAR;   // all As1 reads done; Hs (overlays As0+As1) safe to write

    // epilogue 1: bias+relu -> Hs[m][j]; acc: col(lane&15)=m, row(quad*4+r)=j
#pragma unroll
    for (int mi = 0; mi < 4; ++mi)
#pragma unroll
      for (int ni = 0; ni < 6; ++ni) {
        const int j = wave * 96 + ni * 16 + quad * 4;
        const float4 bb = *(const float4*)&b1s[j];
        float v0 = acc[mi][ni][0] + bb.x; v0 = v0 > 0.f ? v0 : 0.f;
        float v1 = acc[mi][ni][1] + bb.y; v1 = v1 > 0.f ? v1 : 0.f;
        float v2 = acc[mi][ni][2] + bb.z; v2 = v2 > 0.f ? v2 : 0.f;
        float v3 = acc[mi][ni][3] + bb.w; v3 = v3 > 0.f ? v3 : 0.f;
        uint2 pk = {cvt2(v0, v1), cvt2(v2, v3)};
        *(uint2*)&Hs[(mi * 16 + lrow) * 392 + j] = pk;
      }
    LBAR;

    // epilogue 2: layer-2 MFMA, M=64 (m-tile = wave), N=16 (8 valid), K=384
    {
      f32x4 acc2 = (f32x4){0.f, 0.f, 0.f, 0.f};
#pragma unroll
      for (int kk = 0; kk < 12; ++kk) {
        s16x8 af = *(const s16x8*)&Hs[(wave * 16 + lrow) * 392 + kk * 32 + quad * 8];
        s16x8 bf = *(const s16x8*)&W2s[lrow * 392 + kk * 32 + quad * 8];
        acc2 = __builtin_amdgcn_mfma_f32_16x16x32_bf16(af, bf, acc2, 0, 0, 0);
      }
      if (lrow < NCLS) {
        const float bb = b2s[lrow];
#pragma unroll
        for (int r = 0; r < 4; ++r) {
          const int m = wave * 16 + quad * 4 + r;
          if (row0 + m < n_e) {
            const int oi = bucket[(size_t)e * N_SAMPLES + row0 + m];
            out[(size_t)oi * NCLS + lrow] = acc2[r] + bb;
          }
        }
      }
    }
    LBAR;   // Hs reads done before next tile's DMA overwrites it

#pragma unroll
    for (int i = 0; i < 8; ++i) off[i] = (unsigned)nraw[i] * 3072u + g16o;
  }
}

extern "C" void kernel_launch(void* const* d_in, const int* in_sizes, int n_in,
                              void* d_out, int out_size, void* d_ws, size_t ws_size,
                              hipStream_t stream) {
  const float* x  = (const float*)d_in[0];
  const float* W1 = (const float*)d_in[1];
  const float* b1 = (const float*)d_in[2];
  const float* W2 = (const float*)d_in[3];
  const float* b2 = (const float*)d_in[4];
  const int* qt   = (const int*)d_in[5];
  float* out = (float*)d_out;
  char* ws = (char*)d_ws;

  int* cnt = (int*)(ws + WS_CNT);
  int* bucket = (int*)(ws + WS_BUCKET);
  unsigned short* W1F = (unsigned short*)(ws + WS_W1F);

  k_w1frag<<<dim3(8, 144), dim3(256), 0, stream>>>(W1, W1F, cnt);
  k_scatter<<<dim3(256), dim3(256), 0, stream>>>(qt, cnt, bucket);
  k_moe_gemm<<<dim3(8, 64), dim3(256), 0, stream>>>(x, W1F, b1, W2, b2, cnt, bucket, out);
}

// Round 6
// 385.391 us; speedup vs baseline: 1.2805x; 1.2286x over previous
//
#include <hip/hip_runtime.h>

typedef short s16x8 __attribute__((ext_vector_type(8)));
typedef float f32x4 __attribute__((ext_vector_type(4)));

#define N_SAMPLES 65536
#define DIM 768
#define HID 384
#define NEXP 8
#define NCLS 8
#define JT 24   // HID/16
#define KT 24   // DIM/32

// workspace layout (bytes)
#define WS_CNT    0
#define WS_BUCKET 1024
#define WS_W1F    (WS_BUCKET + NEXP * N_SAMPLES * 4)        // 2,098,176
#define WS_XG     (WS_W1F + 8 * 576 * 64 * 8 * 2)           // 6,816,768
// XG = 65536 rows x 768 bf16 = 100,663,296 B -> total ~107.5 MB

// RNE bf16 (prep only)
__device__ __forceinline__ unsigned short f2bf(float f) {
  union { float f; unsigned u; } v; v.f = f;
  unsigned r = v.u + 0x7fffu + ((v.u >> 16) & 1u);
  return (unsigned short)(r >> 16);
}

// fast half-up pair: 2x v_add + 1x v_perm; low16 = bf(a), high16 = bf(b)
__device__ __forceinline__ unsigned cvt2(float a, float b) {
  union { float f; unsigned u; } ua, ub;
  ua.f = a; ub.f = b;
  return __builtin_amdgcn_perm(ub.u + 0x8000u, ua.u + 0x8000u, 0x07060302u);
}

// lgkm-only barrier: does NOT drain vmcnt, register prefetches stay in flight
#define LBAR asm volatile("s_waitcnt lgkmcnt(0)\n\ts_barrier" ::: "memory")

// W1[e][k=768][j=384] f32 -> W1F in MFMA A-fragment order:
// W1F[((e*JT+jt)*KT+kt)*64 + lane][i] = W1[e][kt*32+(lane>>4)*8+i][jt*16+(lane&15)]
__global__ void k_w1frag(const float* __restrict__ W1,
                         unsigned short* __restrict__ W1F,
                         int* __restrict__ cnt) {
  if (blockIdx.x == 0 && blockIdx.y == 0 && threadIdx.x < NEXP)
    cnt[threadIdx.x] = 0;
  const int e = blockIdx.x;
  const int unit = blockIdx.y * 4 + (threadIdx.x >> 6);   // (jt,kt) flat, 0..575
  const int lane = threadIdx.x & 63;
  const int jt = unit / KT, kt = unit % KT;
  const int j = jt * 16 + (lane & 15);
  const int k0 = kt * 32 + (lane >> 4) * 8;
  const float* src = W1 + ((size_t)e * DIM + k0) * HID + j;
  s16x8 v;
#pragma unroll
  for (int i = 0; i < 8; ++i) v[i] = (short)f2bf(src[(size_t)i * HID]);
  *(s16x8*)&W1F[(((size_t)e * JT * KT + unit) * 64 + lane) * 8] = v;
}

// bucket rows by expert
__global__ void k_scatter(const int* __restrict__ qt, int* __restrict__ cnt,
                          int* __restrict__ bucket) {
  __shared__ int lcnt[NEXP], lbase[NEXP];
  const int t = threadIdx.x;
  const int i = blockIdx.x * 256 + t;
  if (t < NEXP) lcnt[t] = 0;
  __syncthreads();
  const int e = qt[i];
  const int rank = atomicAdd(&lcnt[e], 1);
  __syncthreads();
  if (t < NEXP) lbase[t] = atomicAdd(&cnt[t], lcnt[t]);
  __syncthreads();
  bucket[(size_t)e * N_SAMPLES + lbase[e] + rank] = i;
}

// ---- dedicated row-gather: x (f32, permuted rows) -> xg (bf16, packed by
// expert). Each row is read as 3 back-to-back 1KB wave-bursts (3KB fully
// contiguous -> DRAM page efficiency); writes are perfectly sequential.
// No LDS, no barriers: pure streaming, thousands of independent waves. ----
__global__ __launch_bounds__(256) void k_gather(
    const float* __restrict__ x, const int* __restrict__ cnt,
    const int* __restrict__ bucket, unsigned short* __restrict__ xg) {
  const int e = blockIdx.x;
  int base = 0, n_e = 0;
#pragma unroll
  for (int i = 0; i < NEXP; ++i) {
    int c = cnt[i];
    if (i < e) base += c;
    if (i == e) n_e = c;
  }
  const int wave = threadIdx.x >> 6, lane = threadIdx.x & 63;

  for (int rt = blockIdx.y; rt * 64 < n_e; rt += gridDim.y) {
    const int s0 = rt * 64 + wave * 16;           // this wave's 16 slots
    int sl = s0 + (lane & 15);
    if (sl > n_e - 1) sl = n_e - 1;
    const int bkt = bucket[(size_t)e * N_SAMPLES + sl];  // slot->src row
    // process rows in pairs: 6 x 1KB loads in flight, then cvt+store
#pragma unroll
    for (int r = 0; r < 16; r += 2) {
      const int sA = s0 + r, sB = s0 + r + 1;
      const int srcA = __shfl(bkt, r), srcB = __shfl(bkt, r + 1);
      const float4* pa = (const float4*)(x + (size_t)srcA * DIM);
      const float4* pb = (const float4*)(x + (size_t)srcB * DIM);
      float4 c0, c1, c2, c3, c4, c5;
      if (sA < n_e) { c0 = pa[lane]; c1 = pa[64 + lane]; c2 = pa[128 + lane]; }
      if (sB < n_e) { c3 = pb[lane]; c4 = pb[64 + lane]; c5 = pb[128 + lane]; }
      if (sA < n_e) {
        uint2* da = (uint2*)(xg + (size_t)(base + sA) * DIM);
        da[lane]       = (uint2){cvt2(c0.x, c0.y), cvt2(c0.z, c0.w)};
        da[64 + lane]  = (uint2){cvt2(c1.x, c1.y), cvt2(c1.z, c1.w)};
        da[128 + lane] = (uint2){cvt2(c2.x, c2.y), cvt2(c2.z, c2.w)};
      }
      if (sB < n_e) {
        uint2* db = (uint2*)(xg + (size_t)(base + sB) * DIM);
        db[lane]       = (uint2){cvt2(c3.x, c3.y), cvt2(c3.z, c3.w)};
        db[64 + lane]  = (uint2){cvt2(c4.x, c4.y), cvt2(c4.z, c4.w)};
        db[128 + lane] = (uint2){cvt2(c5.x, c5.y), cvt2(c5.z, c5.w)};
      }
    }
  }
}

// ---- GEMM building blocks (named slots only -- rule #20) ----

// load 8 bf16 (16B) of this thread's xg row for k-step KS into named slot
#define ALOADN(S, KS) a##S = *(const s16x8*)(ap + (KS) * 32);

// raw ds_write_b128 into A tile ([64 m][40 k-pad] bf16) -- no cvt needed
#define ASTOREN(BUF, S) *(s16x8*)&(BUF)[ar * 40 + aq * 8] = a##S;

// 6 coalesced b128 fragment loads of W1F for k-step KS (from e-pinned L2)
#define WLOADN(WF, KS)                                                      \
  _Pragma("unroll") for (int ni = 0; ni < 6; ++ni)                          \
      WF[ni] = *(const s16x8*)(wfbase + ((size_t)ni * KT + (KS)) * 512);

// 4 ds_read_b128 (x frags, 2-way free) + 24 MFMA; WF = A-operand (j), x = B (m)
#define COMPUTE(AS, WF)                                                     \
  { _Pragma("unroll") for (int mi = 0; mi < 4; ++mi) {                      \
      s16x8 xfr = *(const s16x8*)&(AS)[(mi * 16 + lrow) * 40 + quad * 8];   \
      _Pragma("unroll") for (int ni = 0; ni < 6; ++ni)                      \
          acc[mi][ni] = __builtin_amdgcn_mfma_f32_16x16x32_bf16(            \
              WF[ni], xfr, acc[mi][ni], 0, 0, 0); } }

// one k-step: stage LDS from a 3-step-old slot (counted vmcnt, ~21 younger
// loads stay in flight), refill it 4 ahead, compute from a 2-step-old W slot
#define KSTEP(ASC, ASN, SN, SF, KA, WF, KW) \
  ASTOREN(ASN, SN)                          \
  ALOADN(SF, KA)                            \
  COMPUTE(ASC, WF)                          \
  WLOADN(WF, KW)                            \
  LBAR;

// block = (expert e -> pinned XCD, 64 packed rows, all 384 H)
__global__ __launch_bounds__(256, 2) void k_moe_gemm(
    const unsigned short* __restrict__ xg, const unsigned short* __restrict__ W1F,
    const float* __restrict__ b1, const float* __restrict__ W2,
    const float* __restrict__ b2, const int* __restrict__ cnt,
    const int* __restrict__ bucket, float* __restrict__ out) {
  // Hs (64x392 bf16 = 50 KB) overlays the two tiny A staging buffers.
  __shared__ __align__(16) short smem[25088];
  __shared__ __align__(16) short W2s[16 * 392];
  __shared__ float b1s[HID];
  __shared__ float b2s[NCLS];
  short* As0 = smem;            // [64 m][40 k-pad] bf16
  short* As1 = smem + 2560;
  short* Hs  = smem;            // [64 m][392 j] bf16

  const int e = blockIdx.x;
  int base = 0, n_e = 0;
#pragma unroll
  for (int i = 0; i < NEXP; ++i) {
    int c = cnt[i];
    if (i < e) base += c;
    if (i == e) n_e = c;
  }
  if (n_e <= 0) return;         // uniform exit, no barrier crossed yet
  const int t = threadIdx.x;
  const int lane = t & 63;
  const int wave = t >> 6;
  const int lrow = lane & 15;
  const int quad = lane >> 4;
  const int ar = t >> 2;        // A staging row (0..63)
  const int aq = t & 3;         // A staging k-chunk (8 bf16)

  for (int j = t; j < HID; j += 256) {
    b1s[j] = b1[e * HID + j];
    const float* wr = W2 + ((size_t)e * HID + j) * NCLS;
#pragma unroll
    for (int c = 0; c < NCLS; ++c) W2s[c * 392 + j] = (short)f2bf(wr[c]);
#pragma unroll
    for (int c = NCLS; c < 16; ++c) W2s[c * 392 + j] = 0;
  }
  if (t < NCLS) b2s[t] = b2[e * NCLS + t];

  // this wave's W1F base: jt = wave*6 + ni, per-kt stride 512 shorts
  const unsigned short* wfbase =
      W1F + ((size_t)(e * JT + wave * 6) * KT) * 512 + lane * 8;

  for (int rt = blockIdx.y; rt * 64 < n_e; rt += gridDim.y) {
    const int row0 = rt * 64;
    int rowc = row0 + ar;
    if (rowc > n_e - 1) rowc = n_e - 1;   // clamp: dup compute, masked store
    // SEQUENTIAL A source: packed bf16 rows, 96KB contiguous per tile
    const unsigned short* ap = xg + (size_t)(base + rowc) * DIM + aq * 8;

    f32x4 acc[4][6];
#pragma unroll
    for (int mi = 0; mi < 4; ++mi)
#pragma unroll
      for (int ni = 0; ni < 6; ++ni) acc[mi][ni] = (f32x4){0.f, 0.f, 0.f, 0.f};

    s16x8 a0, a1, a2, a3;       // A ring: 4 named slots, distance-3 consume
    s16x8 wfA[6], wfB[6];       // W ring: 2 named slots, distance-2

    // prologue: fill rings (A: 0-3, W: 0-1), stage step 0.
    // ASTORE of slot0 waits with 15 younger loads outstanding -> counted.
    ALOADN(0, 0) ALOADN(1, 1) ALOADN(2, 2) ALOADN(3, 3)
    WLOADN(wfA, 0) WLOADN(wfB, 1)
    ASTOREN(As0, 0)
    LBAR;   // As0 visible; all register prefetches stay in flight

    // steady state: 5 unguarded period-4 bodies cover k-steps 0..19
    for (int kb = 0; kb < 20; kb += 4) {
      KSTEP(As0, As1, 1, 0, kb + 4, wfA, kb + 2)
      KSTEP(As1, As0, 2, 1, kb + 5, wfB, kb + 3)
      KSTEP(As0, As1, 3, 2, kb + 6, wfA, kb + 4)
      KSTEP(As1, As0, 0, 3, kb + 7, wfB, kb + 5)
    }

    // epilogue: steps 20..23, no further A loads
    ASTOREN(As1, 1) COMPUTE(As0, wfA) WLOADN(wfA, 22) LBAR;   // step 20
    ASTOREN(As0, 2) COMPUTE(As1, wfB) WLOADN(wfB, 23) LBAR;   // step 21
    ASTOREN(As1, 3) COMPUTE(As0, wfA) LBAR;                   // step 22
    COMPUTE(As1, wfB) LBAR;                                   // step 23

    // epilogue 1: bias+relu -> Hs[m][j]; acc: col(lane&15)=m, row(quad*4+r)=j
#pragma unroll
    for (int mi = 0; mi < 4; ++mi)
#pragma unroll
      for (int ni = 0; ni < 6; ++ni) {
        const int j = wave * 96 + ni * 16 + quad * 4;
        const float4 bb = *(const float4*)&b1s[j];
        float v0 = acc[mi][ni][0] + bb.x; v0 = v0 > 0.f ? v0 : 0.f;
        float v1 = acc[mi][ni][1] + bb.y; v1 = v1 > 0.f ? v1 : 0.f;
        float v2 = acc[mi][ni][2] + bb.z; v2 = v2 > 0.f ? v2 : 0.f;
        float v3 = acc[mi][ni][3] + bb.w; v3 = v3 > 0.f ? v3 : 0.f;
        uint2 pk = {cvt2(v0, v1), cvt2(v2, v3)};
        *(uint2*)&Hs[(mi * 16 + lrow) * 392 + j] = pk;
      }
    LBAR;

    // epilogue 2: layer-2 MFMA, M=64 (m-tile = wave), N=16 (8 valid), K=384
    {
      f32x4 acc2 = (f32x4){0.f, 0.f, 0.f, 0.f};
#pragma unroll
      for (int kk = 0; kk < 12; ++kk) {
        s16x8 af = *(const s16x8*)&Hs[(wave * 16 + lrow) * 392 + kk * 32 + quad * 8];
        s16x8 bf = *(const s16x8*)&W2s[lrow * 392 + kk * 32 + quad * 8];
        acc2 = __builtin_amdgcn_mfma_f32_16x16x32_bf16(af, bf, acc2, 0, 0, 0);
      }
      if (lrow < NCLS) {
        const float bb = b2s[lrow];
#pragma unroll
        for (int r = 0; r < 4; ++r) {
          const int m = wave * 16 + quad * 4 + r;
          if (row0 + m < n_e) {
            const int oi = bucket[(size_t)e * N_SAMPLES + row0 + m];
            out[(size_t)oi * NCLS + lrow] = acc2[r] + bb;
          }
        }
      }
    }
    LBAR;   // Hs reads done before next tile's A staging overwrites it
  }
}

extern "C" void kernel_launch(void* const* d_in, const int* in_sizes, int n_in,
                              void* d_out, int out_size, void* d_ws, size_t ws_size,
                              hipStream_t stream) {
  const float* x  = (const float*)d_in[0];
  const float* W1 = (const float*)d_in[1];
  const float* b1 = (const float*)d_in[2];
  const float* W2 = (const float*)d_in[3];
  const float* b2 = (const float*)d_in[4];
  const int* qt   = (const int*)d_in[5];
  float* out = (float*)d_out;
  char* ws = (char*)d_ws;

  int* cnt = (int*)(ws + WS_CNT);
  int* bucket = (int*)(ws + WS_BUCKET);
  unsigned short* W1F = (unsigned short*)(ws + WS_W1F);
  unsigned short* xg  = (unsigned short*)(ws + WS_XG);

  k_w1frag<<<dim3(8, 144), dim3(256), 0, stream>>>(W1, W1F, cnt);
  k_scatter<<<dim3(256), dim3(256), 0, stream>>>(qt, cnt, bucket);
  k_gather<<<dim3(8, 128), dim3(256), 0, stream>>>(x, cnt, bucket, xg);
  k_moe_gemm<<<dim3(8, 64), dim3(256), 0, stream>>>(xg, W1F, b1, W2, b2, cnt, bucket, out);
}

// Round 7
// 383.716 us; speedup vs baseline: 1.2861x; 1.0044x over previous
//
#include <hip/hip_runtime.h>

typedef short s16x8 __attribute__((ext_vector_type(8)));
typedef float f32x4 __attribute__((ext_vector_type(4)));

#define N_SAMPLES 65536
#define DIM 768
#define HID 384
#define NEXP 8
#define NCLS 8
#define JT 24   // HID/16
#define KT 24   // DIM/32

// workspace layout (bytes)
#define WS_CNT    0
#define WS_BUCKET 1024
#define WS_W1F    (WS_BUCKET + NEXP * N_SAMPLES * 4)        // 2,098,176
#define WS_XG     (WS_W1F + 8 * 576 * 64 * 8 * 2)           // 6,816,768
// XG = 65536 rows x 768 bf16 = 100,663,296 B -> total ~107.5 MB

// RNE bf16 (prep only)
__device__ __forceinline__ unsigned short f2bf(float f) {
  union { float f; unsigned u; } v; v.f = f;
  unsigned r = v.u + 0x7fffu + ((v.u >> 16) & 1u);
  return (unsigned short)(r >> 16);
}

// fast half-up pair: 2x v_add + 1x v_perm; low16 = bf(a), high16 = bf(b)
__device__ __forceinline__ unsigned cvt2(float a, float b) {
  union { float f; unsigned u; } ua, ub;
  ua.f = a; ub.f = b;
  return __builtin_amdgcn_perm(ub.u + 0x8000u, ua.u + 0x8000u, 0x07060302u);
}

// lgkm-only barrier: does NOT drain vmcnt, register prefetches stay in flight
#define LBAR asm volatile("s_waitcnt lgkmcnt(0)\n\ts_barrier" ::: "memory")
#define SP1 __builtin_amdgcn_s_setprio(1);
#define SP0 __builtin_amdgcn_s_setprio(0);

// W1[e][k=768][j=384] f32 -> W1F in MFMA A-fragment order:
// W1F[((e*JT+jt)*KT+kt)*64 + lane][i] = W1[e][kt*32+(lane>>4)*8+i][jt*16+(lane&15)]
__global__ void k_w1frag(const float* __restrict__ W1,
                         unsigned short* __restrict__ W1F,
                         int* __restrict__ cnt) {
  if (blockIdx.x == 0 && blockIdx.y == 0 && threadIdx.x < NEXP)
    cnt[threadIdx.x] = 0;
  const int e = blockIdx.x;
  const int unit = blockIdx.y * 4 + (threadIdx.x >> 6);   // (jt,kt) flat, 0..575
  const int lane = threadIdx.x & 63;
  const int jt = unit / KT, kt = unit % KT;
  const int j = jt * 16 + (lane & 15);
  const int k0 = kt * 32 + (lane >> 4) * 8;
  const float* src = W1 + ((size_t)e * DIM + k0) * HID + j;
  s16x8 v;
#pragma unroll
  for (int i = 0; i < 8; ++i) v[i] = (short)f2bf(src[(size_t)i * HID]);
  *(s16x8*)&W1F[(((size_t)e * JT * KT + unit) * 64 + lane) * 8] = v;
}

// bucket rows by expert
__global__ void k_scatter(const int* __restrict__ qt, int* __restrict__ cnt,
                          int* __restrict__ bucket) {
  __shared__ int lcnt[NEXP], lbase[NEXP];
  const int t = threadIdx.x;
  const int i = blockIdx.x * 256 + t;
  if (t < NEXP) lcnt[t] = 0;
  __syncthreads();
  const int e = qt[i];
  const int rank = atomicAdd(&lcnt[e], 1);
  __syncthreads();
  if (t < NEXP) lbase[t] = atomicAdd(&cnt[t], lcnt[t]);
  __syncthreads();
  bucket[(size_t)e * N_SAMPLES + lbase[e] + rank] = i;
}

// ---- flat-slot streaming gather: x (f32, permuted rows) -> xg (bf16,
// packed). 8192 waves x 2 iters x 4 rows = 65536 rows exactly (no clamps).
// Per wave-iter: 12 x 1KB loads in flight (named regs), then 12 x 512B
// sequential stores. 2048 blocks = deep MLP + TLP. ----
__global__ __launch_bounds__(256) void k_gather(
    const float* __restrict__ x, const int* __restrict__ cnt,
    const int* __restrict__ bucket, unsigned short* __restrict__ xg) {
  const int lane = threadIdx.x & 63;
  const int wid = (blockIdx.x << 2) | (threadIdx.x >> 6);   // 0..8191
  int b1_ = 0, b2_ = 0, b3_ = 0, b4_ = 0, b5_ = 0, b6_ = 0, b7_ = 0;
  {
    int a = cnt[0];
    b1_ = a; a += cnt[1]; b2_ = a; a += cnt[2]; b3_ = a; a += cnt[3];
    b4_ = a; a += cnt[4]; b5_ = a; a += cnt[5]; b6_ = a; a += cnt[6];
    b7_ = a;
  }
#pragma unroll
  for (int it = 0; it < 2; ++it) {
    const int s0 = (wid + it * 8192) * 4;
    // lane r<4 resolves slot s0+r -> source row (others idle briefly)
    int src = 0;
    if (lane < 4) {
      const int sl = s0 + lane;
      int e = 0, bs = 0;
      if (sl >= b1_) { e = 1; bs = b1_; }
      if (sl >= b2_) { e = 2; bs = b2_; }
      if (sl >= b3_) { e = 3; bs = b3_; }
      if (sl >= b4_) { e = 4; bs = b4_; }
      if (sl >= b5_) { e = 5; bs = b5_; }
      if (sl >= b6_) { e = 6; bs = b6_; }
      if (sl >= b7_) { e = 7; bs = b7_; }
      src = bucket[(size_t)e * N_SAMPLES + (sl - bs)];
    }
    const int r0 = __shfl(src, 0), r1 = __shfl(src, 1),
              r2 = __shfl(src, 2), r3 = __shfl(src, 3);
    const float4* p0 = (const float4*)(x + (size_t)r0 * DIM);
    const float4* p1 = (const float4*)(x + (size_t)r1 * DIM);
    const float4* p2 = (const float4*)(x + (size_t)r2 * DIM);
    const float4* p3 = (const float4*)(x + (size_t)r3 * DIM);
    float4 c00 = p0[lane], c01 = p0[64 + lane], c02 = p0[128 + lane];
    float4 c10 = p1[lane], c11 = p1[64 + lane], c12 = p1[128 + lane];
    float4 c20 = p2[lane], c21 = p2[64 + lane], c22 = p2[128 + lane];
    float4 c30 = p3[lane], c31 = p3[64 + lane], c32 = p3[128 + lane];
    uint2* d0 = (uint2*)(xg + (size_t)(s0 + 0) * DIM);
    uint2* d1 = (uint2*)(xg + (size_t)(s0 + 1) * DIM);
    uint2* d2 = (uint2*)(xg + (size_t)(s0 + 2) * DIM);
    uint2* d3 = (uint2*)(xg + (size_t)(s0 + 3) * DIM);
    d0[lane]       = (uint2){cvt2(c00.x, c00.y), cvt2(c00.z, c00.w)};
    d0[64 + lane]  = (uint2){cvt2(c01.x, c01.y), cvt2(c01.z, c01.w)};
    d0[128 + lane] = (uint2){cvt2(c02.x, c02.y), cvt2(c02.z, c02.w)};
    d1[lane]       = (uint2){cvt2(c10.x, c10.y), cvt2(c10.z, c10.w)};
    d1[64 + lane]  = (uint2){cvt2(c11.x, c11.y), cvt2(c11.z, c11.w)};
    d1[128 + lane] = (uint2){cvt2(c12.x, c12.y), cvt2(c12.z, c12.w)};
    d2[lane]       = (uint2){cvt2(c20.x, c20.y), cvt2(c20.z, c20.w)};
    d2[64 + lane]  = (uint2){cvt2(c21.x, c21.y), cvt2(c21.z, c21.w)};
    d2[128 + lane] = (uint2){cvt2(c22.x, c22.y), cvt2(c22.z, c22.w)};
    d3[lane]       = (uint2){cvt2(c30.x, c30.y), cvt2(c30.z, c30.w)};
    d3[64 + lane]  = (uint2){cvt2(c31.x, c31.y), cvt2(c31.z, c31.w)};
    d3[128 + lane] = (uint2){cvt2(c32.x, c32.y), cvt2(c32.z, c32.w)};
  }
}

// ---- GEMM building blocks (named slots only -- rule #20) ----

// load 8 bf16 (16B) of this thread's xg row for k-step KS into named slot
#define ALOADN(S, KS) a##S = *(const s16x8*)(ap + (KS) * 32);

// raw ds_write_b128 into A tile ([64 m][40 k-pad] bf16)
#define ASTOREN(BUF, S) *(s16x8*)&(BUF)[ar * 40 + aq * 8] = a##S;

// 6 coalesced b128 fragment loads of W1F for k-step KS (from e-pinned L2)
#define WLOADN(WF, KS)                                                      \
  _Pragma("unroll") for (int ni = 0; ni < 6; ++ni)                          \
      WF[ni] = *(const s16x8*)(wfbase + ((size_t)ni * KT + (KS)) * 512);

// 4 ds_read_b128 (x frags, 2-way free) + 24 MFMA; WF = A-operand (j), x = B (m)
#define COMPUTE(AS, WF)                                                     \
  { _Pragma("unroll") for (int mi = 0; mi < 4; ++mi) {                      \
      s16x8 xfr = *(const s16x8*)&(AS)[(mi * 16 + lrow) * 40 + quad * 8];   \
      _Pragma("unroll") for (int ni = 0; ni < 6; ++ni)                      \
          acc[mi][ni] = __builtin_amdgcn_mfma_f32_16x16x32_bf16(            \
              WF[ni], xfr, acc[mi][ni], 0, 0, 0); } }

// block = (expert e -> pinned XCD, 64 packed rows, all 384 H).
// 2 k-steps per barrier (13 barriers/tile vs 25): 4 A-buffers cycle with
// period 4; slot s always holds k-step == s (mod 4); W ring distance-2.
__global__ __launch_bounds__(256, 2) void k_moe_gemm(
    const unsigned short* __restrict__ xg, const unsigned short* __restrict__ W1F,
    const float* __restrict__ b1, const float* __restrict__ W2,
    const float* __restrict__ b2, const int* __restrict__ cnt,
    const int* __restrict__ bucket, float* __restrict__ out) {
  // Hs (64x392 bf16 = 50 KB) overlays the four tiny A staging buffers.
  __shared__ __align__(16) short smem[25088];
  __shared__ __align__(16) short W2s[16 * 392];
  __shared__ float b1s[HID];
  __shared__ float b2s[NCLS];
  short* As0 = smem;            // [64 m][40 k-pad] bf16 each
  short* As1 = smem + 2560;
  short* As2 = smem + 5120;
  short* As3 = smem + 7680;
  short* Hs  = smem;            // [64 m][392 j] bf16

  const int e = blockIdx.x;
  int base = 0, n_e = 0;
#pragma unroll
  for (int i = 0; i < NEXP; ++i) {
    int c = cnt[i];
    if (i < e) base += c;
    if (i == e) n_e = c;
  }
  if (n_e <= 0) return;         // uniform exit, no barrier crossed yet
  const int t = threadIdx.x;
  const int lane = t & 63;
  const int wave = t >> 6;
  const int lrow = lane & 15;
  const int quad = lane >> 4;
  const int ar = t >> 2;        // A staging row (0..63)
  const int aq = t & 3;         // A staging k-chunk (8 bf16)

  for (int j = t; j < HID; j += 256) {
    b1s[j] = b1[e * HID + j];
    const float* wr = W2 + ((size_t)e * HID + j) * NCLS;
#pragma unroll
    for (int c = 0; c < NCLS; ++c) W2s[c * 392 + j] = (short)f2bf(wr[c]);
#pragma unroll
    for (int c = NCLS; c < 16; ++c) W2s[c * 392 + j] = 0;
  }
  if (t < NCLS) b2s[t] = b2[e * NCLS + t];

  // this wave's W1F base: jt = wave*6 + ni, per-kt stride 512 shorts
  const unsigned short* wfbase =
      W1F + ((size_t)(e * JT + wave * 6) * KT) * 512 + lane * 8;

  for (int rt = blockIdx.y; rt * 64 < n_e; rt += gridDim.y) {
    const int row0 = rt * 64;
    int rowc = row0 + ar;
    if (rowc > n_e - 1) rowc = n_e - 1;   // clamp: dup compute, masked store
    // SEQUENTIAL A source: packed bf16 rows, 96KB contiguous per tile
    const unsigned short* ap = xg + (size_t)(base + rowc) * DIM + aq * 8;

    f32x4 acc[4][6];
#pragma unroll
    for (int mi = 0; mi < 4; ++mi)
#pragma unroll
      for (int ni = 0; ni < 6; ++ni) acc[mi][ni] = (f32x4){0.f, 0.f, 0.f, 0.f};

    s16x8 a0, a1, a2, a3;       // A ring: 4 named slots
    s16x8 wfA[6], wfB[6];       // W ring: 2 named slots, abs distance 2

    // prologue: fill rings, stage k-steps 0,1
    ALOADN(0, 0) ALOADN(1, 1) ALOADN(2, 2) ALOADN(3, 3)
    WLOADN(wfA, 0) WLOADN(wfB, 1)
    ASTOREN(As0, 0) ASTOREN(As1, 1)
    LBAR;   // As0/As1 visible; all register prefetches stay in flight

    // 5 x 2-phase bodies cover phases 0..9 (k-steps 0..19)
    for (int kb = 0; kb < 20; kb += 4) {
      // even phase: compute ks kb,kb+1; stage kb+2,kb+3; load kb+4,kb+5
      ASTOREN(As2, 2) ASTOREN(As3, 3)
      ALOADN(0, kb + 4) ALOADN(1, kb + 5)
      SP1 COMPUTE(As0, wfA) SP0 WLOADN(wfA, kb + 2)
      SP1 COMPUTE(As1, wfB) SP0 WLOADN(wfB, kb + 3)
      LBAR;
      // odd phase: compute ks kb+2,kb+3; stage kb+4,kb+5; load kb+6,kb+7
      ASTOREN(As0, 0) ASTOREN(As1, 1)
      ALOADN(2, kb + 6) ALOADN(3, kb + 7)
      SP1 COMPUTE(As2, wfA) SP0 WLOADN(wfA, kb + 4)
      SP1 COMPUTE(As3, wfB) SP0 WLOADN(wfB, kb + 5)
      LBAR;
    }
    // phase 10: ks 20,21; stage 22,23
    ASTOREN(As2, 2) ASTOREN(As3, 3)
    SP1 COMPUTE(As0, wfA) SP0 WLOADN(wfA, 22)
    SP1 COMPUTE(As1, wfB) SP0 WLOADN(wfB, 23)
    LBAR;
    // phase 11: ks 22,23
    SP1 COMPUTE(As2, wfA) SP0
    SP1 COMPUTE(As3, wfB) SP0
    LBAR;

    // epilogue 1: bias+relu -> Hs[m][j]; acc: col(lane&15)=m, row(quad*4+r)=j
#pragma unroll
    for (int mi = 0; mi < 4; ++mi)
#pragma unroll
      for (int ni = 0; ni < 6; ++ni) {
        const int j = wave * 96 + ni * 16 + quad * 4;
        const float4 bb = *(const float4*)&b1s[j];
        float v0 = acc[mi][ni][0] + bb.x; v0 = v0 > 0.f ? v0 : 0.f;
        float v1 = acc[mi][ni][1] + bb.y; v1 = v1 > 0.f ? v1 : 0.f;
        float v2 = acc[mi][ni][2] + bb.z; v2 = v2 > 0.f ? v2 : 0.f;
        float v3 = acc[mi][ni][3] + bb.w; v3 = v3 > 0.f ? v3 : 0.f;
        uint2 pk = {cvt2(v0, v1), cvt2(v2, v3)};
        *(uint2*)&Hs[(mi * 16 + lrow) * 392 + j] = pk;
      }
    LBAR;

    // epilogue 2: layer-2 MFMA, M=64 (m-tile = wave), N=16 (8 valid), K=384
    {
      f32x4 acc2 = (f32x4){0.f, 0.f, 0.f, 0.f};
#pragma unroll
      for (int kk = 0; kk < 12; ++kk) {
        s16x8 af = *(const s16x8*)&Hs[(wave * 16 + lrow) * 392 + kk * 32 + quad * 8];
        s16x8 bf = *(const s16x8*)&W2s[lrow * 392 + kk * 32 + quad * 8];
        acc2 = __builtin_amdgcn_mfma_f32_16x16x32_bf16(af, bf, acc2, 0, 0, 0);
      }
      if (lrow < NCLS) {
        const float bb = b2s[lrow];
#pragma unroll
        for (int r = 0; r < 4; ++r) {
          const int m = wave * 16 + quad * 4 + r;
          if (row0 + m < n_e) {
            const int oi = bucket[(size_t)e * N_SAMPLES + row0 + m];
            out[(size_t)oi * NCLS + lrow] = acc2[r] + bb;
          }
        }
      }
    }
    LBAR;   // Hs reads done before next tile's A staging overwrites it
  }
}

extern "C" void kernel_launch(void* const* d_in, const int* in_sizes, int n_in,
                              void* d_out, int out_size, void* d_ws, size_t ws_size,
                              hipStream_t stream) {
  const float* x  = (const float*)d_in[0];
  const float* W1 = (const float*)d_in[1];
  const float* b1 = (const float*)d_in[2];
  const float* W2 = (const float*)d_in[3];
  const float* b2 = (const float*)d_in[4];
  const int* qt   = (const int*)d_in[5];
  float* out = (float*)d_out;
  char* ws = (char*)d_ws;

  int* cnt = (int*)(ws + WS_CNT);
  int* bucket = (int*)(ws + WS_BUCKET);
  unsigned short* W1F = (unsigned short*)(ws + WS_W1F);
  unsigned short* xg  = (unsigned short*)(ws + WS_XG);

  k_w1frag<<<dim3(8, 144), dim3(256), 0, stream>>>(W1, W1F, cnt);
  k_scatter<<<dim3(256), dim3(256), 0, stream>>>(qt, cnt, bucket);
  k_gather<<<dim3(2048), dim3(256), 0, stream>>>(x, cnt, bucket, xg);
  k_moe_gemm<<<dim3(8, 64), dim3(256), 0, stream>>>(xg, W1F, b1, W2, b2, cnt, bucket, out);
}

// Round 8
// 377.795 us; speedup vs baseline: 1.3062x; 1.0157x over previous
//
#include <hip/hip_runtime.h>

typedef short s16x8 __attribute__((ext_vector_type(8)));
typedef float f32x4 __attribute__((ext_vector_type(4)));

#define N_SAMPLES 65536
#define DIM 768
#define HID 384
#define NEXP 8
#define NCLS 8
#define JT 24   // HID/16
#define KT 24   // DIM/32

// workspace layout (bytes)
#define WS_CNT    0
#define WS_BUCKET 1024
#define WS_POS    (WS_BUCKET + NEXP * N_SAMPLES * 4)        // 2,098,176
#define WS_W1F    (WS_POS + N_SAMPLES * 4)                  // 2,360,320
#define WS_XG     (WS_W1F + 8 * 576 * 64 * 8 * 2)           // 7,078,912
// XG = 65536 rows x 768 bf16 = 100,663,296 B -> total ~107.7 MB

// RNE bf16 (prep only)
__device__ __forceinline__ unsigned short f2bf(float f) {
  union { float f; unsigned u; } v; v.f = f;
  unsigned r = v.u + 0x7fffu + ((v.u >> 16) & 1u);
  return (unsigned short)(r >> 16);
}

// fast half-up pair: 2x v_add + 1x v_perm; low16 = bf(a), high16 = bf(b)
__device__ __forceinline__ unsigned cvt2(float a, float b) {
  union { float f; unsigned u; } ua, ub;
  ua.f = a; ub.f = b;
  return __builtin_amdgcn_perm(ub.u + 0x8000u, ua.u + 0x8000u, 0x07060302u);
}

// lgkm-only barrier: does NOT drain vmcnt, register prefetches stay in flight
#define LBAR asm volatile("s_waitcnt lgkmcnt(0)\n\ts_barrier" ::: "memory")
#define SP1 __builtin_amdgcn_s_setprio(1);
#define SP0 __builtin_amdgcn_s_setprio(0);

// W1[e][k=768][j=384] f32 -> W1F in MFMA A-fragment order:
// W1F[((e*JT+jt)*KT+kt)*64 + lane][i] = W1[e][kt*32+(lane>>4)*8+i][jt*16+(lane&15)]
__global__ void k_w1frag(const float* __restrict__ W1,
                         unsigned short* __restrict__ W1F,
                         int* __restrict__ cnt) {
  if (blockIdx.x == 0 && blockIdx.y == 0 && threadIdx.x < NEXP)
    cnt[threadIdx.x] = 0;
  const int e = blockIdx.x;
  const int unit = blockIdx.y * 4 + (threadIdx.x >> 6);   // (jt,kt) flat, 0..575
  const int lane = threadIdx.x & 63;
  const int jt = unit / KT, kt = unit % KT;
  const int j = jt * 16 + (lane & 15);
  const int k0 = kt * 32 + (lane >> 4) * 8;
  const float* src = W1 + ((size_t)e * DIM + k0) * HID + j;
  s16x8 v;
#pragma unroll
  for (int i = 0; i < 8; ++i) v[i] = (short)f2bf(src[(size_t)i * HID]);
  *(s16x8*)&W1F[(((size_t)e * JT * KT + unit) * 64 + lane) * 8] = v;
}

// bucket rows by expert; also emit pos[i] = packed slot of row i
__global__ void k_scatter(const int* __restrict__ qt, int* __restrict__ cnt,
                          int* __restrict__ bucket, int* __restrict__ pos) {
  __shared__ int lcnt[NEXP], lbase[NEXP];
  const int t = threadIdx.x;
  const int i = blockIdx.x * 256 + t;
  if (t < NEXP) lcnt[t] = 0;
  __syncthreads();
  const int e = qt[i];
  const int rank = atomicAdd(&lcnt[e], 1);
  __syncthreads();
  if (t < NEXP) lbase[t] = atomicAdd(&cnt[t], lcnt[t]);
  __syncthreads();
  const int slot = lbase[e] + rank;            // LOCAL slot within expert e
  bucket[(size_t)e * N_SAMPLES + slot] = i;
  // global packed slot = prefix(e) + local; prefix applied in k_repack
  pos[i] = slot;
}

// ---- repack: sequential READ of x (full DRAM page efficiency), scattered
// WRITE of bf16 rows to xg (fire-and-forget; L2 absorbs). This inverts
// rounds 0-7's gather, whose random KB-granule READS were page-miss-bound
// at 1.4-2.5 TB/s no matter the issue depth (HBM channel interleave ~256B:
// a "3KB contiguous row" is 12 channels x 256B at random pages). ----
__global__ __launch_bounds__(256) void k_repack(
    const float* __restrict__ x, const int* __restrict__ qt,
    const int* __restrict__ cnt, const int* __restrict__ pos,
    unsigned short* __restrict__ xg) {
  const int lane = threadIdx.x & 63;
  const int wave = threadIdx.x >> 6;
  const int r0 = (blockIdx.x * 4 + wave) * 8;   // 2048 blk x 4 waves x 8 rows
  // expert prefix bases
  int b0_ = 0, b1_, b2_, b3_, b4_, b5_, b6_, b7_;
  {
    int a = cnt[0];
    b1_ = a; a += cnt[1]; b2_ = a; a += cnt[2]; b3_ = a; a += cnt[3];
    b4_ = a; a += cnt[4]; b5_ = a; a += cnt[5]; b6_ = a; a += cnt[6];
    b7_ = a; (void)b0_;
  }
  int p = 0;
  if (lane < 8) {
    const int i = r0 + lane;
    const int e = qt[i];
    int bs = 0;
    if (e == 1) bs = b1_; else if (e == 2) bs = b2_; else if (e == 3) bs = b3_;
    else if (e == 4) bs = b4_; else if (e == 5) bs = b5_;
    else if (e == 6) bs = b6_; else if (e == 7) bs = b7_;
    p = bs + pos[i];
  }
#pragma unroll
  for (int rr = 0; rr < 8; rr += 2) {
    const float4* pa = (const float4*)(x + (size_t)(r0 + rr) * DIM);
    const float4* pb = (const float4*)(x + (size_t)(r0 + rr + 1) * DIM);
    float4 a0 = pa[lane], a1 = pa[64 + lane], a2 = pa[128 + lane];
    float4 b0 = pb[lane], b1 = pb[64 + lane], b2 = pb[128 + lane];
    const int sA = __shfl(p, rr), sB = __shfl(p, rr + 1);
    uint2* da = (uint2*)(xg + (size_t)sA * DIM);
    uint2* db = (uint2*)(xg + (size_t)sB * DIM);
    da[lane]       = (uint2){cvt2(a0.x, a0.y), cvt2(a0.z, a0.w)};
    da[64 + lane]  = (uint2){cvt2(a1.x, a1.y), cvt2(a1.z, a1.w)};
    da[128 + lane] = (uint2){cvt2(a2.x, a2.y), cvt2(a2.z, a2.w)};
    db[lane]       = (uint2){cvt2(b0.x, b0.y), cvt2(b0.z, b0.w)};
    db[64 + lane]  = (uint2){cvt2(b1.x, b1.y), cvt2(b1.z, b1.w)};
    db[128 + lane] = (uint2){cvt2(b2.x, b2.y), cvt2(b2.z, b2.w)};
  }
}

// ---- GEMM building blocks (named slots only -- rule #20) ----

// load 8 bf16 (16B) of this thread's xg row for k-step KS into named slot
#define ALOADN(S, KS) a##S = *(const s16x8*)(ap + (KS) * 32);

// raw ds_write_b128 into A tile ([64 m][40 k-pad] bf16)
#define ASTOREN(BUF, S) *(s16x8*)&(BUF)[ar * 40 + aq * 8] = a##S;

// 6 coalesced b128 fragment loads of W1F for k-step KS (from e-pinned L2)
#define WLOADN(WF, KS)                                                      \
  _Pragma("unroll") for (int ni = 0; ni < 6; ++ni)                          \
      WF[ni] = *(const s16x8*)(wfbase + ((size_t)ni * KT + (KS)) * 512);

// 4 ds_read_b128 (x frags, 2-way free) + 24 MFMA; WF = A-operand (j), x = B (m)
#define COMPUTE(AS, WF)                                                     \
  { _Pragma("unroll") for (int mi = 0; mi < 4; ++mi) {                      \
      s16x8 xfr = *(const s16x8*)&(AS)[(mi * 16 + lrow) * 40 + quad * 8];   \
      _Pragma("unroll") for (int ni = 0; ni < 6; ++ni)                      \
          acc[mi][ni] = __builtin_amdgcn_mfma_f32_16x16x32_bf16(            \
              WF[ni], xfr, acc[mi][ni], 0, 0, 0); } }

// block = (expert e -> pinned XCD, 64 packed rows, all 384 H).
// 2 k-steps per barrier: 4 A-buffers cycle with period 4; W ring distance-2.
__global__ __launch_bounds__(256, 2) void k_moe_gemm(
    const unsigned short* __restrict__ xg, const unsigned short* __restrict__ W1F,
    const float* __restrict__ b1, const float* __restrict__ W2,
    const float* __restrict__ b2, const int* __restrict__ cnt,
    const int* __restrict__ bucket, float* __restrict__ out) {
  // Hs (64x392 bf16 = 50 KB) overlays the four tiny A staging buffers.
  __shared__ __align__(16) short smem[25088];
  __shared__ __align__(16) short W2s[16 * 392];
  __shared__ float b1s[HID];
  __shared__ float b2s[NCLS];
  short* As0 = smem;            // [64 m][40 k-pad] bf16 each
  short* As1 = smem + 2560;
  short* As2 = smem + 5120;
  short* As3 = smem + 7680;
  short* Hs  = smem;            // [64 m][392 j] bf16

  const int e = blockIdx.x;
  int base = 0, n_e = 0;
#pragma unroll
  for (int i = 0; i < NEXP; ++i) {
    int c = cnt[i];
    if (i < e) base += c;
    if (i == e) n_e = c;
  }
  if (n_e <= 0) return;         // uniform exit, no barrier crossed yet
  const int t = threadIdx.x;
  const int lane = t & 63;
  const int wave = t >> 6;
  const int lrow = lane & 15;
  const int quad = lane >> 4;
  const int ar = t >> 2;        // A staging row (0..63)
  const int aq = t & 3;         // A staging k-chunk (8 bf16)

  for (int j = t; j < HID; j += 256) {
    b1s[j] = b1[e * HID + j];
    const float* wr = W2 + ((size_t)e * HID + j) * NCLS;
#pragma unroll
    for (int c = 0; c < NCLS; ++c) W2s[c * 392 + j] = (short)f2bf(wr[c]);
#pragma unroll
    for (int c = NCLS; c < 16; ++c) W2s[c * 392 + j] = 0;
  }
  if (t < NCLS) b2s[t] = b2[e * NCLS + t];

  // this wave's W1F base: jt = wave*6 + ni, per-kt stride 512 shorts
  const unsigned short* wfbase =
      W1F + ((size_t)(e * JT + wave * 6) * KT) * 512 + lane * 8;

  for (int rt = blockIdx.y; rt * 64 < n_e; rt += gridDim.y) {
    const int row0 = rt * 64;
    int rowc = row0 + ar;
    if (rowc > n_e - 1) rowc = n_e - 1;   // clamp: dup compute, masked store
    // SEQUENTIAL A source: packed bf16 rows, 96KB contiguous per tile
    const unsigned short* ap = xg + (size_t)(base + rowc) * DIM + aq * 8;

    f32x4 acc[4][6];
#pragma unroll
    for (int mi = 0; mi < 4; ++mi)
#pragma unroll
      for (int ni = 0; ni < 6; ++ni) acc[mi][ni] = (f32x4){0.f, 0.f, 0.f, 0.f};

    s16x8 a0, a1, a2, a3;       // A ring: 4 named slots
    s16x8 wfA[6], wfB[6];       // W ring: 2 named slots

    // prologue: fill rings, stage k-steps 0,1
    ALOADN(0, 0) ALOADN(1, 1) ALOADN(2, 2) ALOADN(3, 3)
    WLOADN(wfA, 0) WLOADN(wfB, 1)
    ASTOREN(As0, 0) ASTOREN(As1, 1)
    LBAR;   // As0/As1 visible; all register prefetches stay in flight

    // 5 x 2-phase bodies cover phases 0..9 (k-steps 0..19)
    for (int kb = 0; kb < 20; kb += 4) {
      ASTOREN(As2, 2) ASTOREN(As3, 3)
      ALOADN(0, kb + 4) ALOADN(1, kb + 5)
      SP1 COMPUTE(As0, wfA) SP0 WLOADN(wfA, kb + 2)
      SP1 COMPUTE(As1, wfB) SP0 WLOADN(wfB, kb + 3)
      LBAR;
      ASTOREN(As0, 0) ASTOREN(As1, 1)
      ALOADN(2, kb + 6) ALOADN(3, kb + 7)
      SP1 COMPUTE(As2, wfA) SP0 WLOADN(wfA, kb + 4)
      SP1 COMPUTE(As3, wfB) SP0 WLOADN(wfB, kb + 5)
      LBAR;
    }
    // phase 10: ks 20,21; stage 22,23
    ASTOREN(As2, 2) ASTOREN(As3, 3)
    SP1 COMPUTE(As0, wfA) SP0 WLOADN(wfA, 22)
    SP1 COMPUTE(As1, wfB) SP0 WLOADN(wfB, 23)
    LBAR;
    // phase 11: ks 22,23
    SP1 COMPUTE(As2, wfA) SP0
    SP1 COMPUTE(As3, wfB) SP0
    LBAR;

    // epilogue 1: bias+relu -> Hs[m][j]; acc: col(lane&15)=m, row(quad*4+r)=j
#pragma unroll
    for (int mi = 0; mi < 4; ++mi)
#pragma unroll
      for (int ni = 0; ni < 6; ++ni) {
        const int j = wave * 96 + ni * 16 + quad * 4;
        const float4 bb = *(const float4*)&b1s[j];
        float v0 = acc[mi][ni][0] + bb.x; v0 = v0 > 0.f ? v0 : 0.f;
        float v1 = acc[mi][ni][1] + bb.y; v1 = v1 > 0.f ? v1 : 0.f;
        float v2 = acc[mi][ni][2] + bb.z; v2 = v2 > 0.f ? v2 : 0.f;
        float v3 = acc[mi][ni][3] + bb.w; v3 = v3 > 0.f ? v3 : 0.f;
        uint2 pk = {cvt2(v0, v1), cvt2(v2, v3)};
        *(uint2*)&Hs[(mi * 16 + lrow) * 392 + j] = pk;
      }
    LBAR;

    // epilogue 2: layer-2 MFMA, M=64 (m-tile = wave), N=16 (8 valid), K=384
    {
      f32x4 acc2 = (f32x4){0.f, 0.f, 0.f, 0.f};
#pragma unroll
      for (int kk = 0; kk < 12; ++kk) {
        s16x8 af = *(const s16x8*)&Hs[(wave * 16 + lrow) * 392 + kk * 32 + quad * 8];
        s16x8 bf = *(const s16x8*)&W2s[lrow * 392 + kk * 32 + quad * 8];
        acc2 = __builtin_amdgcn_mfma_f32_16x16x32_bf16(af, bf, acc2, 0, 0, 0);
      }
      if (lrow < NCLS) {
        const float bb = b2s[lrow];
#pragma unroll
        for (int r = 0; r < 4; ++r) {
          const int m = wave * 16 + quad * 4 + r;
          if (row0 + m < n_e) {
            const int oi = bucket[(size_t)e * N_SAMPLES + row0 + m];
            out[(size_t)oi * NCLS + lrow] = acc2[r] + bb;
          }
        }
      }
    }
    LBAR;   // Hs reads done before next tile's A staging overwrites it
  }
}

extern "C" void kernel_launch(void* const* d_in, const int* in_sizes, int n_in,
                              void* d_out, int out_size, void* d_ws, size_t ws_size,
                              hipStream_t stream) {
  const float* x  = (const float*)d_in[0];
  const float* W1 = (const float*)d_in[1];
  const float* b1 = (const float*)d_in[2];
  const float* W2 = (const float*)d_in[3];
  const float* b2 = (const float*)d_in[4];
  const int* qt   = (const int*)d_in[5];
  float* out = (float*)d_out;
  char* ws = (char*)d_ws;

  int* cnt = (int*)(ws + WS_CNT);
  int* bucket = (int*)(ws + WS_BUCKET);
  int* pos = (int*)(ws + WS_POS);
  unsigned short* W1F = (unsigned short*)(ws + WS_W1F);
  unsigned short* xg  = (unsigned short*)(ws + WS_XG);

  k_w1frag<<<dim3(8, 144), dim3(256), 0, stream>>>(W1, W1F, cnt);
  k_scatter<<<dim3(256), dim3(256), 0, stream>>>(qt, cnt, bucket, pos);
  k_repack<<<dim3(2048), dim3(256), 0, stream>>>(x, qt, cnt, pos, xg);
  k_moe_gemm<<<dim3(8, 64), dim3(256), 0, stream>>>(xg, W1F, b1, W2, b2, cnt, bucket, out);
}